// Round 5
// baseline (304.795 us; speedup 1.0000x reference)
//
#include <hip/hip_runtime.h>
#include <stdint.h>

typedef __bf16 bf16_t;
typedef bf16_t bf16x8 __attribute__((ext_vector_type(8)));
typedef bf16_t bf16x4_t __attribute__((ext_vector_type(4)));
typedef float f32x4 __attribute__((ext_vector_type(4)));

#define NB 16
#define NQ 2048
#define NK 2048
#define ND 512
#define SCALE 0.04419417382415922f  // 1/sqrt(512)

typedef __attribute__((address_space(3))) uint32_t lds_u32;
typedef __attribute__((address_space(1))) const uint32_t glb_u32;

__device__ __forceinline__ float4 ld4(const float* p) { return *(const float4*)p; }

__device__ __forceinline__ f32x4 mfma16(bf16x8 a, bf16x8 b, f32x4 c) {
  return __builtin_amdgcn_mfma_f32_16x16x32_bf16(a, b, c, 0, 0, 0);
}

// ---------------------------------------------------------------------------
// Kernel P (merged prep): z=0 Q->Qb, z=1 K->Kb (inverse-swizzled bf16 8KB
// tiles [b][rt(128row)][kt(32K)]), z=2 V->VT (LDS-image bf16 tiles for pv).
// ---------------------------------------------------------------------------
__global__ __launch_bounds__(256) void prep_kernel(const float* __restrict__ Qf,
                                                   const float* __restrict__ Kf,
                                                   const float* __restrict__ Vf,
                                                   bf16_t* __restrict__ Qb,
                                                   bf16_t* __restrict__ Kb,
                                                   bf16_t* __restrict__ VT,
                                                   const int* __restrict__ lens) {
  int x = blockIdx.x;
  int b = blockIdx.y;
  int z = blockIdx.z;
  int t = threadIdx.x;

  if (z == 2) {  // V transpose quarter: kb = x>>2, d-range quarter = x&3
    int kb = x >> 2, dq = (x & 3) * 128;
    if (kb * 32 >= lens[b]) return;
    const float* vsrc = Vf + ((size_t)b * NK + kb * 32) * ND;
    bf16_t* dst = VT + ((size_t)(b * 64 + kb)) * (512 * 32);
    __shared__ alignas(16) bf16_t Ls[32][128];
#pragma unroll
    for (int i = 0; i < 4; ++i) {
      int p = i * 256 + t;
      int k = p >> 5, c4 = p & 31;
      float4 v = ld4(vsrc + (size_t)k * ND + dq + c4 * 4);
      union { bf16_t h[4]; uint2 u; } pk;
      pk.h[0] = (bf16_t)v.x; pk.h[1] = (bf16_t)v.y;
      pk.h[2] = (bf16_t)v.z; pk.h[3] = (bf16_t)v.w;
      *(uint2*)(&Ls[k][c4 * 4]) = pk.u;
    }
    __syncthreads();
    int d = dq + (t >> 1);
    int h = t & 1;
    int sr = d >> 1;
#pragma unroll
    for (int gg = 0; gg < 2; ++gg) {
      int g = h * 2 + gg;
      bf16x8 v;
#pragma unroll
      for (int j = 0; j < 8; ++j) v[j] = Ls[g * 8 + j][d - dq];
      int slot = (((d & 1) << 2) | g) ^ (sr & 7);
      *(bf16x8*)(dst + ((size_t)sr * 8 + slot) * 8) = v;
    }
    return;
  }

  // z = 0/1: Q/K tile prep
  const float* src = z ? Kf : Qf;
  bf16_t* dst = z ? Kb : Qb;
  int rt = x >> 4, kt = x & 15;
  const float* s = src + ((size_t)b * 2048 + (size_t)rt * 128) * 512 + kt * 32;
  bf16_t* dtile = dst + (((size_t)b * 16 + rt) * 16 + kt) * 4096;
#pragma unroll
  for (int i = 0; i < 2; ++i) {
    int d = i * 256 + t;           // dst chunk index 0..511
    int r = d >> 2, slot = d & 3;
    int c = slot ^ ((r >> 1) & 3); // source k-chunk
    const float* p = s + (size_t)r * 512 + c * 8;
    float4 v0 = ld4(p), v1 = ld4(p + 4);
    bf16x8 o;
    o[0] = (bf16_t)v0.x; o[1] = (bf16_t)v0.y; o[2] = (bf16_t)v0.z; o[3] = (bf16_t)v0.w;
    o[4] = (bf16_t)v1.x; o[5] = (bf16_t)v1.y; o[6] = (bf16_t)v1.z; o[7] = (bf16_t)v1.w;
    *(bf16x8*)(dtile + (size_t)d * 8) = o;
  }
}

// ---------------------------------------------------------------------------
// Kernel 1 (256x256 tile, 8 waves, BK=64): per block (b, qt, nt) one 256x256
// exp(S) tile. 64 MFMA per wave between barriers; stages 4x 8KB pre-swizzled
// subtiles per matrix per K-step via global_load_lds. Writes UNNORMALIZED
// bf16 Pu into bytes [4096,8192) of each fp32 W row. Fused exp/mask/rowsum
// -> psum (256-col granularity, 8 nt slots).
// ---------------------------------------------------------------------------
__global__ __launch_bounds__(512, 2) void qk_kernel(const bf16_t* __restrict__ Qb,
                                                    const bf16_t* __restrict__ Kb,
                                                    float* __restrict__ P,
                                                    float* __restrict__ psum,
                                                    const int* __restrict__ lens) {
  // bijective XCD swizzle over 1024 blocks (1024 % 8 == 0), nt fastest
  int bid = blockIdx.x;
  int swz = (bid & 7) * 128 + (bid >> 3);
  int b = swz >> 6;
  int rest = swz & 63;
  int qt = rest >> 3, nt = rest & 7;

  int len = lens[b];
  int q0 = qt * 256;
  int col0 = nt * 256;
  if (col0 >= len) return;  // fully masked: pv zero-fills W, psum never read

  __shared__ alignas(16) bf16_t As[2][16384];
  __shared__ alignas(16) bf16_t Bs[2][16384];
  float* rsm = (float*)&As[0][0];  // aliased: used only after the K-loop

  int t = threadIdx.x;
  int lane = t & 63;
  int wid = t >> 6;
  int wm = wid >> 2, wn = wid & 3;   // 2 x 4 wave grid, wave tile 128x64
  int l15 = lane & 15, l4 = lane >> 4;

  float* prow = P + ((size_t)b * NQ + q0) * NK;
  const bf16_t* qbase = Qb + ((size_t)b * 256) * 4096;  // tile (rt*16+kt)*4096
  const bf16_t* kbase = Kb + ((size_t)b * 256) * 4096;

  f32x4 acc[8][4];
  f32x4 zz = {0.f, 0.f, 0.f, 0.f};
#pragma unroll
  for (int mi = 0; mi < 8; ++mi)
#pragma unroll
    for (int ni = 0; ni < 4; ++ni) acc[mi][ni] = zz;

  auto stage = [&](int j, int buf) {
#pragma unroll
    for (int u = 0; u < 4; ++u) {        // u = (row-half h)*2 + (K-sub s)
      int h = u >> 1, s = u & 1;
      int kt = j * 2 + s;
      const bf16_t* qa = qbase + ((size_t)((qt * 2 + h) * 16 + kt)) * 4096 + t * 8;
      const bf16_t* ka = kbase + ((size_t)((nt * 2 + h) * 16 + kt)) * 4096 + t * 8;
      __builtin_amdgcn_global_load_lds((glb_u32*)qa,
                                       (lds_u32*)(&As[buf][u * 4096 + wid * 512]), 16, 0, 0);
      __builtin_amdgcn_global_load_lds((glb_u32*)ka,
                                       (lds_u32*)(&Bs[buf][u * 4096 + wid * 512]), 16, 0, 0);
    }
  };

  auto compute = [&](int buf) {
    bf16x8 bv[4][2];
#pragma unroll
    for (int ni = 0; ni < 4; ++ni) {
      int cb = (wn & 1) * 64 + ni * 16 + l15;  // row within 128-col-half
      int hb = wn >> 1;
      int xr = (cb >> 1) & 3;
#pragma unroll
      for (int ks = 0; ks < 2; ++ks)
        bv[ni][ks] = *(const bf16x8*)(&Bs[buf][(hb * 2 + ks) * 4096 + cb * 32 + (l4 ^ xr) * 8]);
    }
#pragma unroll
    for (int mi = 0; mi < 8; ++mi) {
      int ra = mi * 16 + l15;                  // row within 128-row-half (h = wm)
      int xr = (ra >> 1) & 3;
      bf16x8 a0 = *(const bf16x8*)(&As[buf][(wm * 2 + 0) * 4096 + ra * 32 + (l4 ^ xr) * 8]);
      bf16x8 a1 = *(const bf16x8*)(&As[buf][(wm * 2 + 1) * 4096 + ra * 32 + (l4 ^ xr) * 8]);
#pragma unroll
      for (int ni = 0; ni < 4; ++ni) {
        acc[mi][ni] = mfma16(a0, bv[ni][0], acc[mi][ni]);
        acc[mi][ni] = mfma16(a1, bv[ni][1], acc[mi][ni]);
      }
    }
  };

  stage(0, 0);
  __syncthreads();
#pragma unroll 1
  for (int j = 0; j < 8; ++j) {
    if (j + 1 < 8) stage(j + 1, (j + 1) & 1);  // issue next while computing
    compute(j & 1);
    __syncthreads();
  }

  // epilogue: scale, mask, exp, rowsum over bf16-rounded e, store bf16 Pu
  float rsum[8][4];
#pragma unroll
  for (int mi = 0; mi < 8; ++mi)
#pragma unroll
    for (int r = 0; r < 4; ++r) rsum[mi][r] = 0.f;

#pragma unroll
  for (int mi = 0; mi < 8; ++mi) {
#pragma unroll
    for (int ni = 0; ni < 4; ++ni) {
      int col = col0 + wn * 64 + ni * 16 + l15;
      bool valid = col < len;
#pragma unroll
      for (int r = 0; r < 4; ++r) {
        float e = valid ? __expf(acc[mi][ni][r] * SCALE) : 0.f;
        bf16_t eb = (bf16_t)e;
        rsum[mi][r] += (float)eb;
        bf16_t* purow =
            (bf16_t*)(prow + (size_t)(wm * 128 + mi * 16 + l4 * 4 + r) * NK) + 2048;
        purow[col] = eb;
      }
    }
  }

  // reduce across the 16 col-lanes, then across the 4 wn waves (phased)
#pragma unroll
  for (int off = 1; off < 16; off <<= 1)
#pragma unroll
    for (int mi = 0; mi < 8; ++mi)
#pragma unroll
      for (int r = 0; r < 4; ++r)
        rsum[mi][r] += __shfl_xor(rsum[mi][r], off, 64);

  if (wn == 0 && l15 == 0) {
#pragma unroll
    for (int mi = 0; mi < 8; ++mi)
#pragma unroll
      for (int r = 0; r < 4; ++r)
        rsm[wm * 128 + mi * 16 + l4 * 4 + r] = rsum[mi][r];
  }
  __syncthreads();
  if (wn == 1 && l15 == 0) {
#pragma unroll
    for (int mi = 0; mi < 8; ++mi)
#pragma unroll
      for (int r = 0; r < 4; ++r)
        rsm[wm * 128 + mi * 16 + l4 * 4 + r] += rsum[mi][r];
  }
  __syncthreads();
  if (wn == 2 && l15 == 0) {
#pragma unroll
    for (int mi = 0; mi < 8; ++mi)
#pragma unroll
      for (int r = 0; r < 4; ++r)
        rsm[wm * 128 + mi * 16 + l4 * 4 + r] += rsum[mi][r];
  }
  __syncthreads();
  if (wn == 3 && l15 == 0) {
#pragma unroll
    for (int mi = 0; mi < 8; ++mi)
#pragma unroll
      for (int r = 0; r < 4; ++r) {
        int row = wm * 128 + mi * 16 + l4 * 4 + r;
        psum[((size_t)b * 16 + nt) * NQ + q0 + row] = rsm[row] + rsum[mi][r];
      }
  }
}

// ---------------------------------------------------------------------------
// Kernel 2 (unchanged from R4 except psum granularity): context = Wnorm x V.
// P staged through 8KB LDS dbuf; V fragments read directly from L2-resident
// VT. Normalizes P in-flight, writes fp32 W + zero tail + ctx.
// ---------------------------------------------------------------------------
__global__ __launch_bounds__(512, 4) void pv_kernel(float* __restrict__ P,
                                                    const bf16_t* __restrict__ VT,
                                                    float* __restrict__ ctx,
                                                    const float* __restrict__ psum,
                                                    const int* __restrict__ lens) {
  int bid = blockIdx.x;
  int b = bid & 15, qt = bid >> 4;
  int q0 = qt * 64;
  int len = lens[b];
  int nsteps = (len + 31) >> 5;
  int nvalid = (len + 255) >> 8;  // valid 256-wide nt tiles in psum

  __shared__ alignas(16) bf16_t Ps[2][64 * 32];
  __shared__ float rcp[64];

  int t = threadIdx.x;
  if (t < 64) {
    float s = 0.f;
    for (int i = 0; i < nvalid; ++i) s += psum[((size_t)b * 16 + i) * NQ + q0 + t];
    rcp[t] = 1.0f / s;
  }
  __syncthreads();

  float* prow = P + ((size_t)b * NQ + q0) * NK;
  const bf16_t* vtb = VT + ((size_t)b * 64) * (512 * 32);

  int lane = t & 63, wid = t >> 6;
  int l15 = lane & 15, l4 = lane >> 4;

  f32x4 acc[4][4];
  f32x4 zz = {0.f, 0.f, 0.f, 0.f};
#pragma unroll
  for (int mi = 0; mi < 4; ++mi)
#pragma unroll
    for (int ni = 0; ni < 4; ++ni) acc[mi][ni] = zz;

  int srow = t >> 3, sc4 = t & 7;
  float rr = rcp[srow];
  const bf16_t* purow = (const bf16_t*)(prow + (size_t)srow * NK) + 2048;

  int vchunk[4];
#pragma unroll
  for (int ni = 0; ni < 4; ++ni) {
    int d = wid * 64 + ni * 16 + l15;
    vchunk[ni] = ((d >> 1) * 8 + ((((d & 1) << 2) | l4) ^ ((d >> 1) & 7))) * 8;
  }

  bf16x4_t pld;

  auto stage_load = [&](int ks) {
    pld = *(const bf16x4_t*)(purow + ks * 32 + sc4 * 4);
  };
  auto stage_finish = [&](int ks, int buf) {
    float4 w;
    w.x = (float)pld[0] * rr; w.y = (float)pld[1] * rr;
    w.z = (float)pld[2] * rr; w.w = (float)pld[3] * rr;
    *(float4*)(prow + (size_t)srow * NK + ks * 32 + sc4 * 4) = w;  // normalized W
    int sr = srow >> 1;
    int slot = (((srow & 1) << 2) | (sc4 >> 1)) ^ (sr & 7);
    union { bf16_t h[4]; uint2 u; } pk;
    pk.h[0] = (bf16_t)w.x; pk.h[1] = (bf16_t)w.y;
    pk.h[2] = (bf16_t)w.z; pk.h[3] = (bf16_t)w.w;
    *(uint2*)(&Ps[buf][((size_t)sr * 8 + slot) * 8 + (sc4 & 1) * 4]) = pk.u;
  };
  auto compute = [&](int ks, int cur) {
    const bf16_t* vsrc = vtb + (size_t)ks * (512 * 32);
    bf16x8 bv[4];
#pragma unroll
    for (int ni = 0; ni < 4; ++ni)
      bv[ni] = *(const bf16x8*)(vsrc + vchunk[ni]);
    bf16x8 af[4];
#pragma unroll
    for (int mi = 0; mi < 4; ++mi) {
      int row = mi * 16 + l15;
      af[mi] = *(const bf16x8*)(&Ps[cur][((row >> 1) * 8 + ((((row & 1) << 2) | l4) ^ ((row >> 1) & 7))) * 8]);
    }
#pragma unroll
    for (int mi = 0; mi < 4; ++mi)
#pragma unroll
      for (int ni = 0; ni < 4; ++ni)
        acc[mi][ni] = mfma16(af[mi], bv[ni], acc[mi][ni]);
  };

  stage_load(0);
  stage_finish(0, 0);
  __syncthreads();
#pragma unroll 1
  for (int ks = 0; ks < nsteps; ++ks) {
    int cur = ks & 1;
    if (ks + 1 < nsteps) stage_load(ks + 1);
    compute(ks, cur);
    if (ks + 1 < nsteps) stage_finish(ks + 1, cur ^ 1);
    __syncthreads();
  }

  // zero-fill masked W tail (own rows only; own Pu reads already consumed)
  {
    float4 z = make_float4(0.f, 0.f, 0.f, 0.f);
    for (int c = nsteps * 32 + sc4 * 4; c < NK; c += 32)
      *(float4*)(prow + (size_t)srow * NK + c) = z;
  }

  float* crow = ctx + ((size_t)b * NQ + q0) * ND + wid * 64;
#pragma unroll
  for (int mi = 0; mi < 4; ++mi)
#pragma unroll
    for (int ni = 0; ni < 4; ++ni)
#pragma unroll
      for (int r = 0; r < 4; ++r)
        crow[(size_t)(mi * 16 + l4 * 4 + r) * ND + ni * 16 + l15] = acc[mi][ni][r];
}

// ---------------------------------------------------------------------------
extern "C" void kernel_launch(void* const* d_in, const int* in_sizes, int n_in,
                              void* d_out, int out_size, void* d_ws, size_t ws_size,
                              hipStream_t stream) {
  const float* Q = (const float*)d_in[0];
  const float* K = (const float*)d_in[1];
  const float* V = (const float*)d_in[2];
  const int* lens = (const int*)d_in[3];

  float* ctx = (float*)d_out;             // [B,Q,D]
  float* P = ctx + (size_t)NB * NQ * ND;  // [B,Q,K] weights region

  // ws layout: psum [B][16][NQ] f32 (2 MB) | Qb 32 MB | Kb 32 MB | VT 32 MB
  float* psum = (float*)d_ws;
  char* base = (char*)d_ws + (size_t)NB * 16 * NQ * sizeof(float);
  bf16_t* Qb = (bf16_t*)base;
  bf16_t* Kb = (bf16_t*)(base + (size_t)NB * NQ * ND * 2);
  bf16_t* VT = (bf16_t*)(base + (size_t)2 * NB * NQ * ND * 2);

  prep_kernel<<<dim3(256, 16, 3), 256, 0, stream>>>(Q, K, V, Qb, Kb, VT, lens);
  qk_kernel<<<dim3(1024), 512, 0, stream>>>(Qb, Kb, P, psum, lens);
  pv_kernel<<<dim3(512), 512, 0, stream>>>(P, VT, ctx, psum, lens);
}

// Round 7
// 286.660 us; speedup vs baseline: 1.0633x; 1.0633x over previous
//
#include <hip/hip_runtime.h>
#include <stdint.h>

typedef __bf16 bf16_t;
typedef bf16_t bf16x8 __attribute__((ext_vector_type(8)));
typedef bf16_t bf16x4_t __attribute__((ext_vector_type(4)));
typedef float f32x4 __attribute__((ext_vector_type(4)));

#define NB 16
#define NQ 2048
#define NK 2048
#define ND 512
#define SCALE 0.04419417382415922f  // 1/sqrt(512)

typedef __attribute__((address_space(3))) uint32_t lds_u32;
typedef __attribute__((address_space(1))) const uint32_t glb_u32;

__device__ __forceinline__ f32x4 ldnt4(const float* p) {
  return __builtin_nontemporal_load((const f32x4*)p);
}
__device__ __forceinline__ void stnt4(float* p, f32x4 v) {
  __builtin_nontemporal_store(v, (f32x4*)p);
}

__device__ __forceinline__ f32x4 mfma16(bf16x8 a, bf16x8 b, f32x4 c) {
  return __builtin_amdgcn_mfma_f32_16x16x32_bf16(a, b, c, 0, 0, 0);
}

// ---------------------------------------------------------------------------
// Kernel P (merged prep): z=0 Q->Qb, z=1 K->Kb (inverse-swizzled bf16 8KB
// tiles), z=2 V->VT (LDS-image bf16 tiles for pv). fp32 inputs read with NT
// hints (read-once; keep L2 for the bf16 tiles).
// ---------------------------------------------------------------------------
__global__ __launch_bounds__(256) void prep_kernel(const float* __restrict__ Qf,
                                                   const float* __restrict__ Kf,
                                                   const float* __restrict__ Vf,
                                                   bf16_t* __restrict__ Qb,
                                                   bf16_t* __restrict__ Kb,
                                                   bf16_t* __restrict__ VT,
                                                   const int* __restrict__ lens) {
  int x = blockIdx.x;
  int b = blockIdx.y;
  int z = blockIdx.z;
  int t = threadIdx.x;

  if (z == 2) {  // V transpose quarter: kb = x>>2, d-range quarter = x&3
    int kb = x >> 2, dq = (x & 3) * 128;
    if (kb * 32 >= lens[b]) return;
    const float* vsrc = Vf + ((size_t)b * NK + kb * 32) * ND;
    bf16_t* dst = VT + ((size_t)(b * 64 + kb)) * (512 * 32);
    __shared__ alignas(16) bf16_t Ls[32][128];
#pragma unroll
    for (int i = 0; i < 4; ++i) {
      int p = i * 256 + t;
      int k = p >> 5, c4 = p & 31;
      f32x4 v = ldnt4(vsrc + (size_t)k * ND + dq + c4 * 4);
      union { bf16_t h[4]; uint2 u; } pk;
      pk.h[0] = (bf16_t)v[0]; pk.h[1] = (bf16_t)v[1];
      pk.h[2] = (bf16_t)v[2]; pk.h[3] = (bf16_t)v[3];
      *(uint2*)(&Ls[k][c4 * 4]) = pk.u;
    }
    __syncthreads();
    int d = dq + (t >> 1);
    int h = t & 1;
    int sr = d >> 1;
#pragma unroll
    for (int gg = 0; gg < 2; ++gg) {
      int g = h * 2 + gg;
      bf16x8 v;
#pragma unroll
      for (int j = 0; j < 8; ++j) v[j] = Ls[g * 8 + j][d - dq];
      int slot = (((d & 1) << 2) | g) ^ (sr & 7);
      *(bf16x8*)(dst + ((size_t)sr * 8 + slot) * 8) = v;
    }
    return;
  }

  // z = 0/1: Q/K tile prep
  const float* src = z ? Kf : Qf;
  bf16_t* dst = z ? Kb : Qb;
  int rt = x >> 4, kt = x & 15;
  const float* s = src + ((size_t)b * 2048 + (size_t)rt * 128) * 512 + kt * 32;
  bf16_t* dtile = dst + (((size_t)b * 16 + rt) * 16 + kt) * 4096;
#pragma unroll
  for (int i = 0; i < 2; ++i) {
    int d = i * 256 + t;           // dst chunk index 0..511
    int r = d >> 2, slot = d & 3;
    int c = slot ^ ((r >> 1) & 3); // source k-chunk
    const float* p = s + (size_t)r * 512 + c * 8;
    f32x4 v0 = ldnt4(p), v1 = ldnt4(p + 4);
    bf16x8 o;
    o[0] = (bf16_t)v0[0]; o[1] = (bf16_t)v0[1]; o[2] = (bf16_t)v0[2]; o[3] = (bf16_t)v0[3];
    o[4] = (bf16_t)v1[0]; o[5] = (bf16_t)v1[1]; o[6] = (bf16_t)v1[2]; o[7] = (bf16_t)v1[3];
    *(bf16x8*)(dtile + (size_t)d * 8) = o;
  }
}

// ---------------------------------------------------------------------------
// Kernel 1 (R4 structure: 128x128, 4 waves, BK=32, 3 blocks/CU): per block
// (b, qt, nt) one 128x128 exp(S) tile. Pu (bf16, unnormalized) stored with
// NT hints into bytes [4096,8192) of each fp32 W row so the write stream
// does NOT evict Qb/Kb panels from the per-XCD L2. Fused exp/mask/rowsum.
// ---------------------------------------------------------------------------
__global__ __launch_bounds__(256, 3) void qk_kernel(const bf16_t* __restrict__ Qb,
                                                    const bf16_t* __restrict__ Kb,
                                                    float* __restrict__ P,
                                                    float* __restrict__ psum,
                                                    const int* __restrict__ lens) {
  int bid = blockIdx.x;
  int swz = (bid & 7) * 512 + (bid >> 3);
  int b = swz >> 8;
  int tile = swz & 255;
  int qt = tile >> 4, nt = tile & 15;

  int len = lens[b];
  int q0 = qt * 128;
  int col0 = nt * 128;
  if (col0 >= len) return;

  __shared__ alignas(16) bf16_t As[2][4096];
  __shared__ alignas(16) bf16_t Bs[2][4096];
  __shared__ float rsm[128];

  int t = threadIdx.x;
  int lane = t & 63;
  int wid = t >> 6;
  int wm = wid >> 1, wn = wid & 1;
  int l15 = lane & 15, l4 = lane >> 4;

  float* prow = P + ((size_t)b * NQ + q0) * NK;
  const bf16_t* qtile = Qb + (((size_t)b * 16 + qt) * 16) * 4096;
  const bf16_t* ktile = Kb + (((size_t)b * 16 + nt) * 16) * 4096;

  f32x4 acc[4][4];
  f32x4 zz = {0.f, 0.f, 0.f, 0.f};
#pragma unroll
  for (int mi = 0; mi < 4; ++mi)
#pragma unroll
    for (int ni = 0; ni < 4; ++ni) acc[mi][ni] = zz;

  int eo = wid * 512 + lane * 8;

  auto stage = [&](int kt2, int buf) {
    const bf16_t* qa = qtile + (size_t)kt2 * 4096;
    const bf16_t* ka = ktile + (size_t)kt2 * 4096;
    bf16_t* la = &As[buf][0];
    bf16_t* lb = &Bs[buf][0];
#pragma unroll
    for (int j = 0; j < 2; ++j) {
      __builtin_amdgcn_global_load_lds((glb_u32*)(qa + j * 2048 + eo),
                                       (lds_u32*)(la + j * 2048 + wid * 512), 16, 0, 0);
      __builtin_amdgcn_global_load_lds((glb_u32*)(ka + j * 2048 + eo),
                                       (lds_u32*)(lb + j * 2048 + wid * 512), 16, 0, 0);
    }
  };

  auto compute = [&](int buf) {
    bf16x8 af[4], bv[4];
#pragma unroll
    for (int mi = 0; mi < 4; ++mi) {
      int row = wm * 64 + mi * 16 + l15;
      int ch = row * 4 + (l4 ^ ((row >> 1) & 3));
      af[mi] = *(const bf16x8*)(&As[buf][ch * 8]);
    }
#pragma unroll
    for (int ni = 0; ni < 4; ++ni) {
      int row = wn * 64 + ni * 16 + l15;
      int ch = row * 4 + (l4 ^ ((row >> 1) & 3));
      bv[ni] = *(const bf16x8*)(&Bs[buf][ch * 8]);
    }
#pragma unroll
    for (int mi = 0; mi < 4; ++mi)
#pragma unroll
      for (int ni = 0; ni < 4; ++ni)
        acc[mi][ni] = mfma16(af[mi], bv[ni], acc[mi][ni]);
  };

  stage(0, 0);
  __syncthreads();
#pragma unroll 1
  for (int kt2 = 0; kt2 < 16; ++kt2) {
    if (kt2 + 1 < 16) stage(kt2 + 1, (kt2 + 1) & 1);
    compute(kt2 & 1);
    __syncthreads();
  }

  // epilogue: scale, mask, exp, rowsum over bf16-rounded e, NT-store bf16 Pu
  float rsum[4][4];
#pragma unroll
  for (int mi = 0; mi < 4; ++mi)
#pragma unroll
    for (int r = 0; r < 4; ++r) rsum[mi][r] = 0.f;

#pragma unroll
  for (int mi = 0; mi < 4; ++mi) {
#pragma unroll
    for (int ni = 0; ni < 4; ++ni) {
      int col = col0 + wn * 64 + ni * 16 + l15;
      bool valid = col < len;
#pragma unroll
      for (int r = 0; r < 4; ++r) {
        float e = valid ? __expf(acc[mi][ni][r] * SCALE) : 0.f;
        bf16_t eb = (bf16_t)e;
        rsum[mi][r] += (float)eb;
        bf16_t* purow =
            (bf16_t*)(prow + (size_t)(wm * 64 + mi * 16 + l4 * 4 + r) * NK) + 2048;
        __builtin_nontemporal_store(eb, &purow[col]);
      }
    }
  }

#pragma unroll
  for (int off = 1; off < 16; off <<= 1)
#pragma unroll
    for (int mi = 0; mi < 4; ++mi)
#pragma unroll
      for (int r = 0; r < 4; ++r)
        rsum[mi][r] += __shfl_xor(rsum[mi][r], off, 64);

  if (wn == 0 && l15 == 0) {
#pragma unroll
    for (int mi = 0; mi < 4; ++mi)
#pragma unroll
      for (int r = 0; r < 4; ++r)
        rsm[wm * 64 + mi * 16 + l4 * 4 + r] = rsum[mi][r];
  }
  __syncthreads();
  if (wn == 1 && l15 == 0) {
#pragma unroll
    for (int mi = 0; mi < 4; ++mi)
#pragma unroll
      for (int r = 0; r < 4; ++r) {
        int row = wm * 64 + mi * 16 + l4 * 4 + r;
        psum[((size_t)b * 16 + nt) * NQ + q0 + row] = rsum[mi][r] + rsm[row];
      }
  }
}

// ---------------------------------------------------------------------------
// Kernel 2 (R4 structure): context = Wnorm x V. P staged through 8KB LDS
// dbuf; V fragments read directly from VT (kept L2-resident by NT-ing all
// streaming W/ctx stores + Pu loads). Normalizes P in-flight.
// ---------------------------------------------------------------------------
__global__ __launch_bounds__(512, 4) void pv_kernel(float* __restrict__ P,
                                                    const bf16_t* __restrict__ VT,
                                                    float* __restrict__ ctx,
                                                    const float* __restrict__ psum,
                                                    const int* __restrict__ lens) {
  int bid = blockIdx.x;
  int b = bid & 15, qt = bid >> 4;
  int q0 = qt * 64;
  int len = lens[b];
  int nsteps = (len + 31) >> 5;
  int nvalid = (len + 127) >> 7;  // valid 128-wide nt tiles in psum

  __shared__ alignas(16) bf16_t Ps[2][64 * 32];
  __shared__ float rcp[64];

  int t = threadIdx.x;
  if (t < 64) {
    float s = 0.f;
    for (int i = 0; i < nvalid; ++i) s += psum[((size_t)b * 16 + i) * NQ + q0 + t];
    rcp[t] = 1.0f / s;
  }
  __syncthreads();

  float* prow = P + ((size_t)b * NQ + q0) * NK;
  const bf16_t* vtb = VT + ((size_t)b * 64) * (512 * 32);

  int lane = t & 63, wid = t >> 6;
  int l15 = lane & 15, l4 = lane >> 4;

  f32x4 acc[4][4];
  f32x4 zz = {0.f, 0.f, 0.f, 0.f};
#pragma unroll
  for (int mi = 0; mi < 4; ++mi)
#pragma unroll
    for (int ni = 0; ni < 4; ++ni) acc[mi][ni] = zz;

  int srow = t >> 3, sc4 = t & 7;
  float rr = rcp[srow];
  const bf16_t* purow = (const bf16_t*)(prow + (size_t)srow * NK) + 2048;

  int vchunk[4];
#pragma unroll
  for (int ni = 0; ni < 4; ++ni) {
    int d = wid * 64 + ni * 16 + l15;
    vchunk[ni] = ((d >> 1) * 8 + ((((d & 1) << 2) | l4) ^ ((d >> 1) & 7))) * 8;
  }

  bf16x4_t pld;

  auto stage_load = [&](int ks) {
    pld = __builtin_nontemporal_load((const bf16x4_t*)(purow + ks * 32 + sc4 * 4));
  };
  auto stage_finish = [&](int ks, int buf) {
    f32x4 w;
    w[0] = (float)pld[0] * rr; w[1] = (float)pld[1] * rr;
    w[2] = (float)pld[2] * rr; w[3] = (float)pld[3] * rr;
    stnt4(prow + (size_t)srow * NK + ks * 32 + sc4 * 4, w);  // normalized W
    int sr = srow >> 1;
    int slot = (((srow & 1) << 2) | (sc4 >> 1)) ^ (sr & 7);
    union { bf16_t h[4]; uint2 u; } pk;
    pk.h[0] = (bf16_t)w[0]; pk.h[1] = (bf16_t)w[1];
    pk.h[2] = (bf16_t)w[2]; pk.h[3] = (bf16_t)w[3];
    *(uint2*)(&Ps[buf][((size_t)sr * 8 + slot) * 8 + (sc4 & 1) * 4]) = pk.u;
  };
  auto compute = [&](int ks, int cur) {
    const bf16_t* vsrc = vtb + (size_t)ks * (512 * 32);
    bf16x8 bv[4];
#pragma unroll
    for (int ni = 0; ni < 4; ++ni)
      bv[ni] = *(const bf16x8*)(vsrc + vchunk[ni]);
    bf16x8 af[4];
#pragma unroll
    for (int mi = 0; mi < 4; ++mi) {
      int row = mi * 16 + l15;
      af[mi] = *(const bf16x8*)(&Ps[cur][((row >> 1) * 8 + ((((row & 1) << 2) | l4) ^ ((row >> 1) & 7))) * 8]);
    }
#pragma unroll
    for (int mi = 0; mi < 4; ++mi)
#pragma unroll
      for (int ni = 0; ni < 4; ++ni)
        acc[mi][ni] = mfma16(af[mi], bv[ni], acc[mi][ni]);
  };

  stage_load(0);
  stage_finish(0, 0);
  __syncthreads();
#pragma unroll 1
  for (int ks = 0; ks < nsteps; ++ks) {
    int cur = ks & 1;
    if (ks + 1 < nsteps) stage_load(ks + 1);
    compute(ks, cur);
    if (ks + 1 < nsteps) stage_finish(ks + 1, cur ^ 1);
    __syncthreads();
  }

  // zero-fill masked W tail (own rows only; own Pu reads already consumed)
  {
    f32x4 z = {0.f, 0.f, 0.f, 0.f};
    for (int c = nsteps * 32 + sc4 * 4; c < NK; c += 32)
      stnt4(prow + (size_t)srow * NK + c, z);
  }

  float* crow = ctx + ((size_t)b * NQ + q0) * ND + wid * 64;
#pragma unroll
  for (int mi = 0; mi < 4; ++mi)
#pragma unroll
    for (int ni = 0; ni < 4; ++ni)
#pragma unroll
      for (int r = 0; r < 4; ++r)
        __builtin_nontemporal_store(
            acc[mi][ni][r],
            &crow[(size_t)(mi * 16 + l4 * 4 + r) * ND + ni * 16 + l15]);
}

// ---------------------------------------------------------------------------
extern "C" void kernel_launch(void* const* d_in, const int* in_sizes, int n_in,
                              void* d_out, int out_size, void* d_ws, size_t ws_size,
                              hipStream_t stream) {
  const float* Q = (const float*)d_in[0];
  const float* K = (const float*)d_in[1];
  const float* V = (const float*)d_in[2];
  const int* lens = (const int*)d_in[3];

  float* ctx = (float*)d_out;             // [B,Q,D]
  float* P = ctx + (size_t)NB * NQ * ND;  // [B,Q,K] weights region

  // ws layout: psum [B][16][NQ] f32 (2 MB) | Qb 32 MB | Kb 32 MB | VT 32 MB
  float* psum = (float*)d_ws;
  char* base = (char*)d_ws + (size_t)NB * 16 * NQ * sizeof(float);
  bf16_t* Qb = (bf16_t*)base;
  bf16_t* Kb = (bf16_t*)(base + (size_t)NB * NQ * ND * 2);
  bf16_t* VT = (bf16_t*)(base + (size_t)2 * NB * NQ * ND * 2);

  prep_kernel<<<dim3(256, 16, 3), 256, 0, stream>>>(Q, K, V, Qb, Kb, VT, lens);
  qk_kernel<<<dim3(4096), 256, 0, stream>>>(Qb, Kb, P, psum, lens);
  pv_kernel<<<dim3(512), 512, 0, stream>>>(P, VT, ctx, psum, lens);
}

// Round 8
// 271.085 us; speedup vs baseline: 1.1244x; 1.0575x over previous
//
#include <hip/hip_runtime.h>
#include <stdint.h>

typedef __bf16 bf16_t;
typedef bf16_t bf16x8 __attribute__((ext_vector_type(8)));
typedef bf16_t bf16x4_t __attribute__((ext_vector_type(4)));
typedef float f32x4 __attribute__((ext_vector_type(4)));

#define NB 16
#define NQ 2048
#define NK 2048
#define ND 512
#define SCALE 0.04419417382415922f  // 1/sqrt(512)

typedef __attribute__((address_space(3))) uint32_t lds_u32;
typedef __attribute__((address_space(1))) const uint32_t glb_u32;

__device__ __forceinline__ float4 ld4(const float* p) { return *(const float4*)p; }

__device__ __forceinline__ f32x4 mfma16(bf16x8 a, bf16x8 b, f32x4 c) {
  return __builtin_amdgcn_mfma_f32_16x16x32_bf16(a, b, c, 0, 0, 0);
}

// ---------------------------------------------------------------------------
// Kernel P (merged prep): z=0 Q->Qb, z=1 K->Kb (inverse-swizzled bf16 8KB
// tiles [b][rt(128row)][kt(32K)]), z=2 V->VT (LDS-image bf16 tiles for pv).
// ---------------------------------------------------------------------------
__global__ __launch_bounds__(256) void prep_kernel(const float* __restrict__ Qf,
                                                   const float* __restrict__ Kf,
                                                   const float* __restrict__ Vf,
                                                   bf16_t* __restrict__ Qb,
                                                   bf16_t* __restrict__ Kb,
                                                   bf16_t* __restrict__ VT,
                                                   const int* __restrict__ lens) {
  int x = blockIdx.x;
  int b = blockIdx.y;
  int z = blockIdx.z;
  int t = threadIdx.x;

  if (z == 2) {  // V transpose quarter: kb = x>>2, d-range quarter = x&3
    int kb = x >> 2, dq = (x & 3) * 128;
    if (kb * 32 >= lens[b]) return;
    const float* vsrc = Vf + ((size_t)b * NK + kb * 32) * ND;
    bf16_t* dst = VT + ((size_t)(b * 64 + kb)) * (512 * 32);
    __shared__ alignas(16) bf16_t Ls[32][128];
#pragma unroll
    for (int i = 0; i < 4; ++i) {
      int p = i * 256 + t;
      int k = p >> 5, c4 = p & 31;
      float4 v = ld4(vsrc + (size_t)k * ND + dq + c4 * 4);
      union { bf16_t h[4]; uint2 u; } pk;
      pk.h[0] = (bf16_t)v.x; pk.h[1] = (bf16_t)v.y;
      pk.h[2] = (bf16_t)v.z; pk.h[3] = (bf16_t)v.w;
      *(uint2*)(&Ls[k][c4 * 4]) = pk.u;
    }
    __syncthreads();
    int d = dq + (t >> 1);
    int h = t & 1;
    int sr = d >> 1;
#pragma unroll
    for (int gg = 0; gg < 2; ++gg) {
      int g = h * 2 + gg;
      bf16x8 v;
#pragma unroll
      for (int j = 0; j < 8; ++j) v[j] = Ls[g * 8 + j][d - dq];
      int slot = (((d & 1) << 2) | g) ^ (sr & 7);
      *(bf16x8*)(dst + ((size_t)sr * 8 + slot) * 8) = v;
    }
    return;
  }

  // z = 0/1: Q/K tile prep
  const float* src = z ? Kf : Qf;
  bf16_t* dst = z ? Kb : Qb;
  int rt = x >> 4, kt = x & 15;
  const float* s = src + ((size_t)b * 2048 + (size_t)rt * 128) * 512 + kt * 32;
  bf16_t* dtile = dst + (((size_t)b * 16 + rt) * 16 + kt) * 4096;
#pragma unroll
  for (int i = 0; i < 2; ++i) {
    int d = i * 256 + t;           // dst chunk index 0..511
    int r = d >> 2, slot = d & 3;
    int c = slot ^ ((r >> 1) & 3); // source k-chunk
    const float* p = s + (size_t)r * 512 + c * 8;
    float4 v0 = ld4(p), v1 = ld4(p + 4);
    bf16x8 o;
    o[0] = (bf16_t)v0.x; o[1] = (bf16_t)v0.y; o[2] = (bf16_t)v0.z; o[3] = (bf16_t)v0.w;
    o[4] = (bf16_t)v1.x; o[5] = (bf16_t)v1.y; o[6] = (bf16_t)v1.z; o[7] = (bf16_t)v1.w;
    *(bf16x8*)(dtile + (size_t)d * 8) = o;
  }
}

// ---------------------------------------------------------------------------
// Kernel 1 (BM=256, BN=128, BK=32, 8 waves 4x2, 2 blocks/CU): per block
// (b, qt, nt) one 256x128 exp(S) tile. Halves global K-panel re-fetch vs the
// 128x128 version (8 passes over Kb instead of 16). Per-wave tile unchanged
// (64x64, acc 4x4). Writes UNNORMALIZED bf16 Pu into bytes [4096,8192) of
// each fp32 W row. Fused exp/mask/rowsum -> psum (128-col nt slots).
// ---------------------------------------------------------------------------
__global__ __launch_bounds__(512, 4) void qk_kernel(const bf16_t* __restrict__ Qb,
                                                    const bf16_t* __restrict__ Kb,
                                                    float* __restrict__ P,
                                                    float* __restrict__ psum,
                                                    const int* __restrict__ lens) {
  // bijective XCD swizzle over 2048 blocks (2048 % 8 == 0), nt fastest
  int bid = blockIdx.x;
  int swz = (bid & 7) * 256 + (bid >> 3);
  int b = swz >> 7;
  int qt = (swz >> 4) & 7;
  int nt = swz & 15;

  int len = lens[b];
  int q0 = qt * 256;
  int col0 = nt * 128;
  if (col0 >= len) return;  // fully masked: pv zero-fills W, psum never read

  __shared__ alignas(16) bf16_t As[2][8192];  // 16KB each: 256 rows x 32 k
  __shared__ alignas(16) bf16_t Bs[2][4096];  // 8KB each: 128 rows x 32 k
  __shared__ float rsm[256];

  int t = threadIdx.x;
  int lane = t & 63;
  int wid = t >> 6;
  int wm = wid >> 1, wn = wid & 1;  // 4 x 2 wave grid, wave tile 64x64
  int l15 = lane & 15, l4 = lane >> 4;

  float* prow = P + ((size_t)b * NQ + q0) * NK;
  const bf16_t* qbase = Qb + ((size_t)b * 256) * 4096;  // tiles (rt*16+kt)
  const bf16_t* ktile = Kb + (((size_t)b * 16 + nt) * 16) * 4096;

  f32x4 acc[4][4];
  f32x4 zz = {0.f, 0.f, 0.f, 0.f};
#pragma unroll
  for (int mi = 0; mi < 4; ++mi)
#pragma unroll
    for (int ni = 0; ni < 4; ++ni) acc[mi][ni] = zz;

  auto stage = [&](int kt2, int buf) {
    // A: two 8KB prep tiles (row-halves of the 256-row panel)
#pragma unroll
    for (int u = 0; u < 2; ++u) {
      const bf16_t* qa = qbase + ((size_t)((qt * 2 + u) * 16 + kt2)) * 4096 + t * 8;
      __builtin_amdgcn_global_load_lds((glb_u32*)qa,
                                       (lds_u32*)(&As[buf][u * 4096 + wid * 512]), 16, 0, 0);
    }
    // B: one 8KB prep tile
    const bf16_t* ka = ktile + (size_t)kt2 * 4096 + t * 8;
    __builtin_amdgcn_global_load_lds((glb_u32*)ka,
                                     (lds_u32*)(&Bs[buf][wid * 512]), 16, 0, 0);
  };

  auto compute = [&](int buf) {
    bf16x8 af[4], bv[4];
#pragma unroll
    for (int mi = 0; mi < 4; ++mi) {
      int row = wm * 64 + mi * 16 + l15;   // 0..255
      int u = row >> 7, r7 = row & 127;
      int ch = r7 * 4 + (l4 ^ ((r7 >> 1) & 3));
      af[mi] = *(const bf16x8*)(&As[buf][u * 4096 + ch * 8]);
    }
#pragma unroll
    for (int ni = 0; ni < 4; ++ni) {
      int row = wn * 64 + ni * 16 + l15;   // 0..127
      int ch = row * 4 + (l4 ^ ((row >> 1) & 3));
      bv[ni] = *(const bf16x8*)(&Bs[buf][ch * 8]);
    }
#pragma unroll
    for (int mi = 0; mi < 4; ++mi)
#pragma unroll
      for (int ni = 0; ni < 4; ++ni)
        acc[mi][ni] = mfma16(af[mi], bv[ni], acc[mi][ni]);
  };

  stage(0, 0);
  __syncthreads();
#pragma unroll 1
  for (int kt2 = 0; kt2 < 16; ++kt2) {
    if (kt2 + 1 < 16) stage(kt2 + 1, (kt2 + 1) & 1);
    compute(kt2 & 1);
    __syncthreads();
  }

  // epilogue: scale, mask, exp, rowsum over bf16-rounded e, store bf16 Pu
  float rsum[4][4];
#pragma unroll
  for (int mi = 0; mi < 4; ++mi)
#pragma unroll
    for (int r = 0; r < 4; ++r) rsum[mi][r] = 0.f;

#pragma unroll
  for (int mi = 0; mi < 4; ++mi) {
#pragma unroll
    for (int ni = 0; ni < 4; ++ni) {
      int col = col0 + wn * 64 + ni * 16 + l15;
      bool valid = col < len;
#pragma unroll
      for (int r = 0; r < 4; ++r) {
        float e = valid ? __expf(acc[mi][ni][r] * SCALE) : 0.f;
        bf16_t eb = (bf16_t)e;
        rsum[mi][r] += (float)eb;
        bf16_t* purow =
            (bf16_t*)(prow + (size_t)(wm * 64 + mi * 16 + l4 * 4 + r) * NK) + 2048;
        purow[col] = eb;
      }
    }
  }

  // reduce across the 16 col-lanes, then across the 2 wn waves
#pragma unroll
  for (int off = 1; off < 16; off <<= 1)
#pragma unroll
    for (int mi = 0; mi < 4; ++mi)
#pragma unroll
      for (int r = 0; r < 4; ++r)
        rsum[mi][r] += __shfl_xor(rsum[mi][r], off, 64);

  if (wn == 0 && l15 == 0) {
#pragma unroll
    for (int mi = 0; mi < 4; ++mi)
#pragma unroll
      for (int r = 0; r < 4; ++r)
        rsm[wm * 64 + mi * 16 + l4 * 4 + r] = rsum[mi][r];
  }
  __syncthreads();
  if (wn == 1 && l15 == 0) {
#pragma unroll
    for (int mi = 0; mi < 4; ++mi)
#pragma unroll
      for (int r = 0; r < 4; ++r) {
        int row = wm * 64 + mi * 16 + l4 * 4 + r;
        psum[((size_t)b * 16 + nt) * NQ + q0 + row] = rsum[mi][r] + rsm[row];
      }
  }
}

// ---------------------------------------------------------------------------
// Kernel 2 (exact R4 structure): context = Wnorm x V. P staged through 8KB
// LDS dbuf; V fragments read directly from L2-resident VT. Normalizes P
// in-flight, writes fp32 W + zero tail + ctx.
// ---------------------------------------------------------------------------
__global__ __launch_bounds__(512, 4) void pv_kernel(float* __restrict__ P,
                                                    const bf16_t* __restrict__ VT,
                                                    float* __restrict__ ctx,
                                                    const float* __restrict__ psum,
                                                    const int* __restrict__ lens) {
  int bid = blockIdx.x;
  int b = bid & 15, qt = bid >> 4;
  int q0 = qt * 64;
  int len = lens[b];
  int nsteps = (len + 31) >> 5;
  int nvalid = (len + 127) >> 7;  // valid 128-wide nt tiles in psum

  __shared__ alignas(16) bf16_t Ps[2][64 * 32];
  __shared__ float rcp[64];

  int t = threadIdx.x;
  if (t < 64) {
    float s = 0.f;
    for (int i = 0; i < nvalid; ++i) s += psum[((size_t)b * 16 + i) * NQ + q0 + t];
    rcp[t] = 1.0f / s;
  }
  __syncthreads();

  float* prow = P + ((size_t)b * NQ + q0) * NK;
  const bf16_t* vtb = VT + ((size_t)b * 64) * (512 * 32);

  int lane = t & 63, wid = t >> 6;
  int l15 = lane & 15, l4 = lane >> 4;

  f32x4 acc[4][4];
  f32x4 zz = {0.f, 0.f, 0.f, 0.f};
#pragma unroll
  for (int mi = 0; mi < 4; ++mi)
#pragma unroll
    for (int ni = 0; ni < 4; ++ni) acc[mi][ni] = zz;

  int srow = t >> 3, sc4 = t & 7;
  float rr = rcp[srow];
  const bf16_t* purow = (const bf16_t*)(prow + (size_t)srow * NK) + 2048;

  int vchunk[4];
#pragma unroll
  for (int ni = 0; ni < 4; ++ni) {
    int d = wid * 64 + ni * 16 + l15;
    vchunk[ni] = ((d >> 1) * 8 + ((((d & 1) << 2) | l4) ^ ((d >> 1) & 7))) * 8;
  }

  bf16x4_t pld;

  auto stage_load = [&](int ks) {
    pld = *(const bf16x4_t*)(purow + ks * 32 + sc4 * 4);
  };
  auto stage_finish = [&](int ks, int buf) {
    float4 w;
    w.x = (float)pld[0] * rr; w.y = (float)pld[1] * rr;
    w.z = (float)pld[2] * rr; w.w = (float)pld[3] * rr;
    *(float4*)(prow + (size_t)srow * NK + ks * 32 + sc4 * 4) = w;  // normalized W
    int sr = srow >> 1;
    int slot = (((srow & 1) << 2) | (sc4 >> 1)) ^ (sr & 7);
    union { bf16_t h[4]; uint2 u; } pk;
    pk.h[0] = (bf16_t)w.x; pk.h[1] = (bf16_t)w.y;
    pk.h[2] = (bf16_t)w.z; pk.h[3] = (bf16_t)w.w;
    *(uint2*)(&Ps[buf][((size_t)sr * 8 + slot) * 8 + (sc4 & 1) * 4]) = pk.u;
  };
  auto compute = [&](int ks, int cur) {
    const bf16_t* vsrc = vtb + (size_t)ks * (512 * 32);
    bf16x8 bv[4];
#pragma unroll
    for (int ni = 0; ni < 4; ++ni)
      bv[ni] = *(const bf16x8*)(vsrc + vchunk[ni]);
    bf16x8 af[4];
#pragma unroll
    for (int mi = 0; mi < 4; ++mi) {
      int row = mi * 16 + l15;
      af[mi] = *(const bf16x8*)(&Ps[cur][((row >> 1) * 8 + ((((row & 1) << 2) | l4) ^ ((row >> 1) & 7))) * 8]);
    }
#pragma unroll
    for (int mi = 0; mi < 4; ++mi)
#pragma unroll
      for (int ni = 0; ni < 4; ++ni)
        acc[mi][ni] = mfma16(af[mi], bv[ni], acc[mi][ni]);
  };

  stage_load(0);
  stage_finish(0, 0);
  __syncthreads();
#pragma unroll 1
  for (int ks = 0; ks < nsteps; ++ks) {
    int cur = ks & 1;
    if (ks + 1 < nsteps) stage_load(ks + 1);
    compute(ks, cur);
    if (ks + 1 < nsteps) stage_finish(ks + 1, cur ^ 1);
    __syncthreads();
  }

  // zero-fill masked W tail (own rows only; own Pu reads already consumed)
  {
    float4 z = make_float4(0.f, 0.f, 0.f, 0.f);
    for (int c = nsteps * 32 + sc4 * 4; c < NK; c += 32)
      *(float4*)(prow + (size_t)srow * NK + c) = z;
  }

  float* crow = ctx + ((size_t)b * NQ + q0) * ND + wid * 64;
#pragma unroll
  for (int mi = 0; mi < 4; ++mi)
#pragma unroll
    for (int ni = 0; ni < 4; ++ni)
#pragma unroll
      for (int r = 0; r < 4; ++r)
        crow[(size_t)(mi * 16 + l4 * 4 + r) * ND + ni * 16 + l15] = acc[mi][ni][r];
}

// ---------------------------------------------------------------------------
extern "C" void kernel_launch(void* const* d_in, const int* in_sizes, int n_in,
                              void* d_out, int out_size, void* d_ws, size_t ws_size,
                              hipStream_t stream) {
  const float* Q = (const float*)d_in[0];
  const float* K = (const float*)d_in[1];
  const float* V = (const float*)d_in[2];
  const int* lens = (const int*)d_in[3];

  float* ctx = (float*)d_out;             // [B,Q,D]
  float* P = ctx + (size_t)NB * NQ * ND;  // [B,Q,K] weights region

  // ws layout: psum [B][16][NQ] f32 (2 MB) | Qb 32 MB | Kb 32 MB | VT 32 MB
  float* psum = (float*)d_ws;
  char* base = (char*)d_ws + (size_t)NB * 16 * NQ * sizeof(float);
  bf16_t* Qb = (bf16_t*)base;
  bf16_t* Kb = (bf16_t*)(base + (size_t)NB * NQ * ND * 2);
  bf16_t* VT = (bf16_t*)(base + (size_t)2 * NB * NQ * ND * 2);

  prep_kernel<<<dim3(256, 16, 3), 256, 0, stream>>>(Q, K, V, Qb, Kb, VT, lens);
  qk_kernel<<<dim3(2048), 512, 0, stream>>>(Qb, Kb, P, psum, lens);
  pv_kernel<<<dim3(512), 512, 0, stream>>>(P, VT, ctx, psum, lens);
}